// Round 8
// baseline (195.193 us; speedup 1.0000x reference)
//
#include <hip/hip_runtime.h>
#include <stdint.h>

#define B_ 4
#define T_ 2048
#define D_ 1024
#define H_ 32

typedef unsigned short u16;
typedef __attribute__((ext_vector_type(8))) short bf16x8;
typedef __attribute__((ext_vector_type(4))) float f32x4;

__device__ __forceinline__ u16 f2bf(float f) {
  union { float f; unsigned u; } c; c.f = f;
  unsigned r = 0x7fffu + ((c.u >> 16) & 1u);
  return (u16)((c.u + r) >> 16);
}
__device__ __forceinline__ float bf2f(u16 h) {
  union { unsigned u; float f; } c; c.u = ((unsigned)h) << 16;
  return c.f;
}

__device__ __forceinline__ void gload_lds16(const void* g, void* l) {
  __builtin_amdgcn_global_load_lds(
      (const __attribute__((address_space(1))) void*)g,
      (__attribute__((address_space(3))) void*)l, 16, 0, 0);
}

// ================= megaprep: all independent prep work, one launch ==========
__global__ void megaprep(const float* __restrict__ x,
                         const float* __restrict__ Wq, const float* __restrict__ Wk,
                         const float* __restrict__ Wv, const float* __restrict__ Wo,
                         const float* __restrict__ bq, const float* __restrict__ bv,
                         const float* __restrict__ bo,
                         u16* __restrict__ xb,
                         u16* __restrict__ wqtb, u16* __restrict__ wktb,
                         u16* __restrict__ wvtb, u16* __restrict__ wob,
                         u16* __restrict__ b2w,
                         float* __restrict__ b2part, float* __restrict__ bvo) {
  const int bid = blockIdx.x;
  const int tid = threadIdx.x;
  if (bid < 4096) {
    const int z = bid >> 10, tile = bid & 1023;
    const int tx = tid & 31, ty = tid >> 5;  // 32x8
    const int c0 = (tile & 31) * 32, r0 = (tile >> 5) * 32;
    if (z == 3) {
#pragma unroll
      for (int r = 0; r < 32; r += 8) {
        const int row = r0 + ty + r, col = c0 + tx;
        const u16 v = f2bf(Wo[(size_t)row * D_ + col]);
        wob[(size_t)row * D_ + col] = v;
        b2w[(size_t)(D_ + row) * D_ + col] = v;  // xo-part rows of concat B
      }
      return;
    }
    const float* in = (z == 0) ? Wq : (z == 1) ? Wk : Wv;
    u16* out = (z == 0) ? wqtb : (z == 1) ? wktb : wvtb;
    __shared__ float tile_s[32][33];
#pragma unroll
    for (int r = 0; r < 32; r += 8)
      tile_s[ty + r][tx] = in[(size_t)(r0 + ty + r) * D_ + c0 + tx];
    __syncthreads();
#pragma unroll
    for (int r = 0; r < 32; r += 8)
      out[(size_t)(c0 + ty + r) * D_ + r0 + tx] = f2bf(tile_s[tx][ty + r]);
  } else if (bid < 6144) {
    const int base = (bid - 4096) * 1024;
#pragma unroll
    for (int k = 0; k < 4; ++k) {
      const int i4 = base + k * 256 + tid;
      float4 v = reinterpret_cast<const float4*>(x)[i4];
      ushort4 o;
      o.x = f2bf(v.x); o.y = f2bf(v.y); o.z = f2bf(v.z); o.w = f2bf(v.w);
      *reinterpret_cast<ushort4*>(xb + (size_t)i4 * 4) = o;
    }
  } else if (bid < 6208) {
    const int sub = bid - 6144;
    const int col = (sub & 3) * 256 + tid;
    const int j0 = (sub >> 2) * 64;
    float acc = 0.f;
#pragma unroll 8
    for (int j = 0; j < 64; ++j) acc += bq[j0 + j] * Wk[(size_t)(j0 + j) * D_ + col];
    b2part[(sub >> 2) * D_ + col] = acc;
  } else {
    const int wid = tid >> 6, lane = tid & 63;
    const int j = (bid - 6208) * 4 + wid;
    float acc = 0.f;
#pragma unroll
    for (int k4 = lane; k4 < 256; k4 += 64) {
      float4 w = *reinterpret_cast<const float4*>(Wo + (size_t)j * D_ + k4 * 4);
      float4 b = *reinterpret_cast<const float4*>(bv + k4 * 4);
      acc += w.x * b.x + w.y * b.y + w.z * b.z + w.w * b.w;
    }
#pragma unroll
    for (int m = 1; m < 64; m <<= 1) acc += __shfl_xor(acc, m);
    if (lane == 0) bvo[j] = acc + bo[j];
  }
}

// ====== finish: reduce split-K=2 partials + finalize bias2 + logb ============
__global__ void finish_kernel(const float* __restrict__ pk, const float* __restrict__ b2part,
                              const float* __restrict__ decay,
                              u16* __restrict__ b2w, u16* __restrict__ wvo,
                              float* __restrict__ bias2, float* __restrict__ logb) {
  const int bid = blockIdx.x;
  const int tid = threadIdx.x;
  if (bid < 2048) {
    const int tgt = bid >> 10;
    const int i4 = (bid & 1023) * 256 + tid;
    const int row = i4 >> 8, c4 = i4 & 255;
    const size_t slab = (size_t)D_ * D_;
    const size_t base = (size_t)tgt * 2 * slab + (size_t)row * D_ + c4 * 4;
    float4 a = *reinterpret_cast<const float4*>(pk + base);
    float4 b = *reinterpret_cast<const float4*>(pk + slab + base);
    ushort4 o;
    o.x = f2bf(a.x + b.x);
    o.y = f2bf(a.y + b.y);
    o.z = f2bf(a.z + b.z);
    o.w = f2bf(a.w + b.w);
    u16* out = tgt ? wvo : b2w;
    *reinterpret_cast<ushort4*>(out + (size_t)row * D_ + c4 * 4) = o;
  } else {
    const int col = (bid - 2048) * 256 + tid;
    float acc = 0.f;
#pragma unroll
    for (int jb = 0; jb < 16; ++jb) acc += b2part[jb * D_ + col];
    bias2[col] = acc;
    bias2[D_ + col] = 0.f;
    if (bid == 2048 && tid < H_)
      logb[tid] = __logf(decay[H_ - 1 - tid] + 1e-10f);
  }
}

// ---------------- 128-tile bf16 NT GEMM core (for small weight GEMMs) --------
__device__ __forceinline__ void gemm_core(
    const u16* __restrict__ A, const u16* __restrict__ Bw,
    float* __restrict__ Cv, int K, int lda, int ldb, int ldc, int bm, int bn) {
  __shared__ u16 lA[128 * 32];
  __shared__ u16 lB[128 * 32];
  const int tid = threadIdx.x;
  const int w = tid >> 6, lane = tid & 63;
  const int wr = w >> 1, wc = w & 1;
  const int lr = lane & 15;
  const int lk = (lane >> 4) << 3;

  f32x4 acc[4][4] = {};

  const int c0 = tid, c1 = tid + 256;
  const size_t aoff0 = (size_t)(bm * 128 + (c0 >> 2)) * lda + ((c0 & 3) << 3);
  const size_t aoff1 = (size_t)(bm * 128 + (c1 >> 2)) * lda + ((c1 & 3) << 3);
  const size_t boff0 = (size_t)(bn * 128 + (c0 >> 2)) * ldb + ((c0 & 3) << 3);
  const size_t boff1 = (size_t)(bn * 128 + (c1 >> 2)) * ldb + ((c1 & 3) << 3);
  u16* lA0 = lA + c0 * 8; u16* lA1 = lA + c1 * 8;
  u16* lB0 = lB + c0 * 8; u16* lB1 = lB + c1 * 8;

  for (int k0 = 0; k0 < K; k0 += 32) {
    gload_lds16(A + aoff0 + k0, lA0);
    gload_lds16(A + aoff1 + k0, lA1);
    gload_lds16(Bw + boff0 + k0, lB0);
    gload_lds16(Bw + boff1 + k0, lB1);
    __syncthreads();
    bf16x8 aF[4], bF[4];
#pragma unroll
    for (int m = 0; m < 4; ++m)
      aF[m] = *reinterpret_cast<const bf16x8*>(&lA[(wr * 64 + m * 16 + lr) * 32 + lk]);
#pragma unroll
    for (int n = 0; n < 4; ++n)
      bF[n] = *reinterpret_cast<const bf16x8*>(&lB[(wc * 64 + n * 16 + lr) * 32 + lk]);
#pragma unroll
    for (int m = 0; m < 4; ++m)
#pragma unroll
      for (int n = 0; n < 4; ++n)
        acc[m][n] = __builtin_amdgcn_mfma_f32_16x16x32_bf16(aF[m], bF[n], acc[m][n], 0, 0, 0);
    __syncthreads();
  }

#pragma unroll
  for (int m = 0; m < 4; ++m) {
    const int row = bm * 128 + wr * 64 + m * 16 + ((lane >> 4) << 2);
#pragma unroll
    for (int n = 0; n < 4; ++n) {
      const int col = bn * 128 + wc * 64 + n * 16 + lr;
#pragma unroll
      for (int r = 0; r < 4; ++r)
        Cv[(size_t)(row + r) * ldc + col] = acc[m][n][r];
    }
  }
}

// ---- both weight GEMMs, split-K=2: z<2 -> Wqk slabs, z>=2 -> Wvo slabs ----
__global__ __launch_bounds__(256, 2)
void gemm_splitk_dual(const u16* __restrict__ wktb, const u16* __restrict__ wqtb,
                      const u16* __restrict__ wob, const u16* __restrict__ wvtb,
                      float* __restrict__ pk) {
  const int z = blockIdx.z;
  const u16 *A, *B;
  if (z < 2) { A = wktb + z * 512; B = wqtb + z * 512; }
  else       { A = wob + (z - 2) * 512; B = wvtb + (z - 2) * 512; }
  float* C = pk + (size_t)z * D_ * D_;
  gemm_core(A, B, C, 512, D_, D_, D_, blockIdx.x, blockIdx.y);
}

// ============ 256x256 bf16 NT GEMM, BK=32, triple-buffer counted-vmcnt ======
// 8 waves (2M x 4N), per-wave 128x64 output. LDS 96KB (3 bufs x (A16K+B16K)).
// Raw s_barrier + counted vmcnt(4): prefetch distance 2, loads stay in flight
// across barriers (T4); full drain only for the last two tiles.
// T2 swizzle: 16B-slot ^= (row>>1)&3, applied BOTH sides (pre-swizzled global
// source + swizzled ds_read; rule #21).
template<int OUT_BF16, int ADDX>
__global__ __launch_bounds__(512, 2)
void gemm256(const u16* __restrict__ A, const u16* __restrict__ Bw,
             const float* __restrict__ bias, const u16* __restrict__ xadd, int ldx,
             void* __restrict__ Cv, int K, int lda, int ldb, int ldc, int nbn) {
  // bijective XCD swizzle (gridDim.x % 8 == 0 at all call sites)
  int bid = blockIdx.x;
  { const int q = gridDim.x >> 3; bid = (bid & 7) * q + (bid >> 3); }
  const int bm = bid / nbn, bn = bid % nbn;

  __shared__ __attribute__((aligned(16))) u16 lds[3 * 16384];  // 96KB
  const int tid = threadIdx.x;
  const int wid = tid >> 6, lane = tid & 63;
  const int wm = wid >> 2, wn = wid & 3;
  const int lr = lane & 15, ls = lane >> 4;

  f32x4 acc[8][4] = {};

  const int r0s = tid >> 2, sl = tid & 3;  // staging: row-base, 16B slot

  const int NT = K >> 5;
  // LDS dest is linear: u16 offset = L*4096 + tid*8 (16B per thread).
  // (R7 bug: offset was (L*4096+tid)*8 -> 16KB overshoot, clobbered buf 2.)
#define STAGE(kt, buf)                                                          \
  {                                                                             \
    const int k0_ = (kt) << 5;                                                  \
    u16* la_ = lds + (buf) * 16384;                                             \
    u16* lb_ = la_ + 8192;                                                      \
    _Pragma("unroll")                                                           \
    for (int L = 0; L < 2; ++L) {                                               \
      const int r_ = L * 128 + r0s;                                             \
      const int cs_ = sl ^ ((r_ >> 1) & 3);                                     \
      gload_lds16(A + (size_t)(bm * 256 + r_) * lda + k0_ + cs_ * 8,            \
                  la_ + (size_t)L * 4096 + (size_t)tid * 8);                    \
      gload_lds16(Bw + (size_t)(bn * 256 + r_) * ldb + k0_ + cs_ * 8,           \
                  lb_ + (size_t)L * 4096 + (size_t)tid * 8);                    \
    }                                                                           \
  }

  STAGE(0, 0);
  STAGE(1, 1);
  asm volatile("s_waitcnt vmcnt(4)" ::: "memory");  // tile 0 landed
  __builtin_amdgcn_sched_barrier(0);
  __builtin_amdgcn_s_barrier();

  for (int t = 0; t < NT; ++t) {
    const int buf = t % 3;
    if (t + 2 < NT) STAGE(t + 2, (t + 2) % 3);
    const char* la = (const char*)(lds + buf * 16384);
    const char* lb = la + 16384;
    bf16x8 aF[8], bF[4];
#pragma unroll
    for (int n = 0; n < 4; ++n) {
      const int row = wn * 64 + n * 16 + lr;
      bF[n] = *reinterpret_cast<const bf16x8*>(lb + row * 64 + ((ls ^ ((row >> 1) & 3)) << 4));
    }
#pragma unroll
    for (int m = 0; m < 8; ++m) {
      const int row = wm * 128 + m * 16 + lr;
      aF[m] = *reinterpret_cast<const bf16x8*>(la + row * 64 + ((ls ^ ((row >> 1) & 3)) << 4));
    }
    __builtin_amdgcn_s_setprio(1);
#pragma unroll
    for (int m = 0; m < 8; ++m)
#pragma unroll
      for (int n = 0; n < 4; ++n)
        acc[m][n] = __builtin_amdgcn_mfma_f32_16x16x32_bf16(aF[m], bF[n], acc[m][n], 0, 0, 0);
    __builtin_amdgcn_s_setprio(0);
    if (t + 2 < NT) asm volatile("s_waitcnt vmcnt(4)" ::: "memory");  // t+1 landed
    else            asm volatile("s_waitcnt vmcnt(0)" ::: "memory");  // drain tail
    __builtin_amdgcn_sched_barrier(0);
    __builtin_amdgcn_s_barrier();
  }
#undef STAGE

#pragma unroll
  for (int m = 0; m < 8; ++m) {
    const int row = bm * 256 + wm * 128 + m * 16 + ls * 4;
#pragma unroll
    for (int n = 0; n < 4; ++n) {
      const int col = bn * 256 + wn * 64 + n * 16 + lr;
      const float bb = bias ? bias[col] : 0.f;
#pragma unroll
      for (int r = 0; r < 4; ++r) {
        float v = acc[m][n][r] + bb;
        if (ADDX) v += bf2f(xadd[(size_t)(row + r) * ldx + col]);
        if (OUT_BF16) ((u16*)Cv)[(size_t)(row + r) * ldc + col] = f2bf(v);
        else          ((float*)Cv)[(size_t)(row + r) * ldc + col] = v;
      }
    }
  }
}

// ---------------- attention over own-history slice (v5) ----------------------
__global__ __launch_bounds__(256, 2)
void attn_kernel(const u16* __restrict__ Q2, const float* __restrict__ hist,
                 const float* __restrict__ logb, u16* __restrict__ hw) {
  __shared__ u16 lh[H_ * D_];    // 64KB bf16 [h][d]
  __shared__ float sTab[4][H_];
  __shared__ float pTab[H_][4];
  const int t = blockIdx.x;
  const int tid = threadIdx.x;
  const int w = tid >> 6, lane = tid & 63;
  const float* hp = hist + (size_t)t * (H_ * D_);

  float s[32] = {};
#pragma unroll 2
  for (int c = 0; c < 4; ++c) {
    const int d0 = lane * 4 + 256 * c;
    float qf[4][4];
#pragma unroll
    for (int b = 0; b < 4; ++b) {
      ushort4 qv = *reinterpret_cast<const ushort4*>(Q2 + ((size_t)b * T_ + t) * 2048 + d0);
      qf[b][0] = bf2f(qv.x); qf[b][1] = bf2f(qv.y);
      qf[b][2] = bf2f(qv.z); qf[b][3] = bf2f(qv.w);
    }
#pragma unroll
    for (int i = 0; i < 8; ++i) {
      const int h = w * 8 + i;
      float4 hv = *reinterpret_cast<const float4*>(hp + h * D_ + d0);
      ushort4 hb;
      hb.x = f2bf(hv.x); hb.y = f2bf(hv.y); hb.z = f2bf(hv.z); hb.w = f2bf(hv.w);
      *reinterpret_cast<ushort4*>(&lh[h * D_ + d0]) = hb;
#pragma unroll
      for (int b = 0; b < 4; ++b)
        s[b * 8 + i] += qf[b][0] * hv.x + qf[b][1] * hv.y +
                        qf[b][2] * hv.z + qf[b][3] * hv.w;
    }
  }
#pragma unroll
  for (int m = 1; m < 64; m <<= 1)
#pragma unroll
    for (int j = 0; j < 32; ++j) s[j] += __shfl_xor(s[j], m);
  if (lane < 32)
    sTab[lane >> 3][w * 8 + (lane & 7)] = s[lane] * 0.03125f + logb[w * 8 + (lane & 7)];
  __syncthreads();

  if (tid < 128) {
    const int b = tid >> 5, h = tid & 31;
    float m0 = -1e30f;
#pragma unroll
    for (int j = 0; j < 32; ++j) m0 = fmaxf(m0, sTab[b][j]);
    float sm = 0.f;
#pragma unroll
    for (int j = 0; j < 32; ++j) sm += __expf(sTab[b][j] - m0);
    pTab[h][b] = __expf(sTab[b][h] - m0) / sm;
  }
  __syncthreads();

  float acc[4][4] = {};
#pragma unroll 8
  for (int h = 0; h < H_; ++h) {
    ushort4 hv = *reinterpret_cast<const ushort4*>(&lh[h * D_ + tid * 4]);
    const float h0 = bf2f(hv.x), h1 = bf2f(hv.y), h2 = bf2f(hv.z), h3 = bf2f(hv.w);
    f32x4 pv = *reinterpret_cast<const f32x4*>(&pTab[h][0]);
#pragma unroll
    for (int bb = 0; bb < 4; ++bb) {
      acc[bb][0] += pv[bb] * h0;
      acc[bb][1] += pv[bb] * h1;
      acc[bb][2] += pv[bb] * h2;
      acc[bb][3] += pv[bb] * h3;
    }
  }
#pragma unroll
  for (int bb = 0; bb < 4; ++bb) {
    ushort4 o;
    o.x = f2bf(acc[bb][0]); o.y = f2bf(acc[bb][1]);
    o.z = f2bf(acc[bb][2]); o.w = f2bf(acc[bb][3]);
    *reinterpret_cast<ushort4*>(hw + ((size_t)bb * T_ + t) * D_ + tid * 4) = o;
  }
}

extern "C" void kernel_launch(void* const* d_in, const int* in_sizes, int n_in,
                              void* d_out, int out_size, void* d_ws, size_t ws_size,
                              hipStream_t stream) {
  (void)in_sizes; (void)n_in; (void)out_size; (void)ws_size;
  const float* x     = (const float*)d_in[0];
  const float* hist  = (const float*)d_in[1];
  const float* Wq    = (const float*)d_in[2];
  const float* bq    = (const float*)d_in[3];
  const float* Wk    = (const float*)d_in[4];
  // d_in[5] = bk: exactly cancelled by softmax shift-invariance
  const float* Wv    = (const float*)d_in[6];
  const float* bv    = (const float*)d_in[7];
  const float* Wo    = (const float*)d_in[8];
  const float* bo    = (const float*)d_in[9];
  const float* decay = (const float*)d_in[10];

  char* p = (char*)d_ws;
  u16* wqtb = (u16*)p; p += (size_t)D_ * D_ * 2;      // Wq^T bf16
  u16* wktb = (u16*)p; p += (size_t)D_ * D_ * 2;      // Wk^T bf16
  u16* wvtb = (u16*)p; p += (size_t)D_ * D_ * 2;      // Wv^T bf16
  u16* wob  = (u16*)p; p += (size_t)D_ * D_ * 2;      // Wo bf16
  u16* wvo  = (u16*)p; p += (size_t)D_ * D_ * 2;      // Wo@Wv bf16
  u16* b2w  = (u16*)p; p += (size_t)2 * D_ * D_ * 2;  // [Wqk ; Wo] rows, ldb=1024
  float* bias2  = (float*)p; p += 2 * D_ * 4;         // [bq@Wk | zeros]
  float* logb   = (float*)p; p += 4096;
  float* bvo    = (float*)p; p += 4096;               // bv@Wo^T + bo
  float* b2part = (float*)p; p += 16 * D_ * 4;
  float* pk     = (float*)p; p += (size_t)4 * D_ * D_ * 4;  // split-K=2 partials (16MB)
  u16* xb   = (u16*)p; p += (size_t)B_ * T_ * D_ * 2;       // x bf16
  u16* Q2b  = (u16*)p; p += (size_t)B_ * T_ * 2048 * 2;     // [Q2 | xo] bf16, ldc=2048
  u16* hwb  = (u16*)p; p += (size_t)B_ * T_ * D_ * 2;       // attn output bf16

  const int M = B_ * T_;  // 8192

  megaprep<<<6464, 256, 0, stream>>>(x, Wq, Wk, Wv, Wo, bq, bv, bo,
                                     xb, wqtb, wktb, wvtb, wob, b2w, b2part, bvo);
  gemm_splitk_dual<<<dim3(8, 8, 4), 256, 0, stream>>>(wktb, wqtb, wob, wvtb, pk);
  finish_kernel<<<2052, 256, 0, stream>>>(pk, b2part, decay, b2w, wvo, bias2, logb);

  // GEMM1: [Q2 | xo] = xb @ b2w^T + [bias2 | 0]  (M=8192,N=2048,K=1024; 256 blocks)
  gemm256<1, 0><<<256, 512, 0, stream>>>(
      xb, b2w, bias2, nullptr, 0, Q2b, D_, D_, D_, 2048, 8);
  // attention -> hw
  attn_kernel<<<T_, 256, 0, stream>>>(Q2b, hist, logb, hwb);
  // out = hw @ wvo^T + xo + bvo  (M=8192,N=1024,K=1024; 128 blocks, f32 out)
  gemm256<0, 1><<<128, 512, 0, stream>>>(
      hwb, wvo, bvo, Q2b + 1024, 2048, (float*)d_out, D_, D_, D_, D_, 4);
}

// Round 9
// 184.392 us; speedup vs baseline: 1.0586x; 1.0586x over previous
//
#include <hip/hip_runtime.h>
#include <stdint.h>

#define B_ 4
#define T_ 2048
#define D_ 1024
#define H_ 32

typedef unsigned short u16;
typedef __attribute__((ext_vector_type(8))) short bf16x8;
typedef __attribute__((ext_vector_type(4))) float f32x4;

__device__ __forceinline__ u16 f2bf(float f) {
  union { float f; unsigned u; } c; c.f = f;
  unsigned r = 0x7fffu + ((c.u >> 16) & 1u);
  return (u16)((c.u + r) >> 16);
}
__device__ __forceinline__ float bf2f(u16 h) {
  union { unsigned u; float f; } c; c.u = ((unsigned)h) << 16;
  return c.f;
}

__device__ __forceinline__ void gload_lds16(const void* g, void* l) {
  __builtin_amdgcn_global_load_lds(
      (const __attribute__((address_space(1))) void*)g,
      (__attribute__((address_space(3))) void*)l, 16, 0, 0);
}

// ================= megaprep: all independent prep work, one launch ==========
__global__ void megaprep(const float* __restrict__ x,
                         const float* __restrict__ Wq, const float* __restrict__ Wk,
                         const float* __restrict__ Wv, const float* __restrict__ Wo,
                         const float* __restrict__ bq, const float* __restrict__ bv,
                         const float* __restrict__ bo,
                         u16* __restrict__ xb,
                         u16* __restrict__ wqtb, u16* __restrict__ wktb,
                         u16* __restrict__ wvtb, u16* __restrict__ wob,
                         u16* __restrict__ b2w,
                         float* __restrict__ b2part, float* __restrict__ bvo) {
  const int bid = blockIdx.x;
  const int tid = threadIdx.x;
  if (bid < 4096) {
    const int z = bid >> 10, tile = bid & 1023;
    const int tx = tid & 31, ty = tid >> 5;  // 32x8
    const int c0 = (tile & 31) * 32, r0 = (tile >> 5) * 32;
    if (z == 3) {
#pragma unroll
      for (int r = 0; r < 32; r += 8) {
        const int row = r0 + ty + r, col = c0 + tx;
        const u16 v = f2bf(Wo[(size_t)row * D_ + col]);
        wob[(size_t)row * D_ + col] = v;
        b2w[(size_t)(D_ + row) * D_ + col] = v;  // xo-part rows of concat B
      }
      return;
    }
    const float* in = (z == 0) ? Wq : (z == 1) ? Wk : Wv;
    u16* out = (z == 0) ? wqtb : (z == 1) ? wktb : wvtb;
    __shared__ float tile_s[32][33];
#pragma unroll
    for (int r = 0; r < 32; r += 8)
      tile_s[ty + r][tx] = in[(size_t)(r0 + ty + r) * D_ + c0 + tx];
    __syncthreads();
#pragma unroll
    for (int r = 0; r < 32; r += 8)
      out[(size_t)(c0 + ty + r) * D_ + r0 + tx] = f2bf(tile_s[tx][ty + r]);
  } else if (bid < 6144) {
    const int base = (bid - 4096) * 1024;
#pragma unroll
    for (int k = 0; k < 4; ++k) {
      const int i4 = base + k * 256 + tid;
      float4 v = reinterpret_cast<const float4*>(x)[i4];
      ushort4 o;
      o.x = f2bf(v.x); o.y = f2bf(v.y); o.z = f2bf(v.z); o.w = f2bf(v.w);
      *reinterpret_cast<ushort4*>(xb + (size_t)i4 * 4) = o;
    }
  } else if (bid < 6208) {
    const int sub = bid - 6144;
    const int col = (sub & 3) * 256 + tid;
    const int j0 = (sub >> 2) * 64;
    float acc = 0.f;
#pragma unroll 8
    for (int j = 0; j < 64; ++j) acc += bq[j0 + j] * Wk[(size_t)(j0 + j) * D_ + col];
    b2part[(sub >> 2) * D_ + col] = acc;
  } else {
    const int wid = tid >> 6, lane = tid & 63;
    const int j = (bid - 6208) * 4 + wid;
    float acc = 0.f;
#pragma unroll
    for (int k4 = lane; k4 < 256; k4 += 64) {
      float4 w = *reinterpret_cast<const float4*>(Wo + (size_t)j * D_ + k4 * 4);
      float4 b = *reinterpret_cast<const float4*>(bv + k4 * 4);
      acc += w.x * b.x + w.y * b.y + w.z * b.z + w.w * b.w;
    }
#pragma unroll
    for (int m = 1; m < 64; m <<= 1) acc += __shfl_xor(acc, m);
    if (lane == 0) bvo[j] = acc + bo[j];
  }
}

// ====== finish: reduce split-K=2 partials + finalize bias2 + logb ============
__global__ void finish_kernel(const float* __restrict__ pk, const float* __restrict__ b2part,
                              const float* __restrict__ decay,
                              u16* __restrict__ b2w, u16* __restrict__ wvo,
                              float* __restrict__ bias2, float* __restrict__ logb) {
  const int bid = blockIdx.x;
  const int tid = threadIdx.x;
  if (bid < 2048) {
    const int tgt = bid >> 10;
    const int i4 = (bid & 1023) * 256 + tid;
    const int row = i4 >> 8, c4 = i4 & 255;
    const size_t slab = (size_t)D_ * D_;
    const size_t base = (size_t)tgt * 2 * slab + (size_t)row * D_ + c4 * 4;
    float4 a = *reinterpret_cast<const float4*>(pk + base);
    float4 b = *reinterpret_cast<const float4*>(pk + slab + base);
    ushort4 o;
    o.x = f2bf(a.x + b.x);
    o.y = f2bf(a.y + b.y);
    o.z = f2bf(a.z + b.z);
    o.w = f2bf(a.w + b.w);
    u16* out = tgt ? wvo : b2w;
    *reinterpret_cast<ushort4*>(out + (size_t)row * D_ + c4 * 4) = o;
  } else {
    const int col = (bid - 2048) * 256 + tid;
    float acc = 0.f;
#pragma unroll
    for (int jb = 0; jb < 16; ++jb) acc += b2part[jb * D_ + col];
    bias2[col] = acc;
    bias2[D_ + col] = 0.f;
    if (bid == 2048 && tid < H_)
      logb[tid] = __logf(decay[H_ - 1 - tid] + 1e-10f);
  }
}

// ---------------- 128-tile bf16 NT GEMM core (small weight GEMMs, f32 out) ---
__device__ __forceinline__ void gemm_core(
    const u16* __restrict__ A, const u16* __restrict__ Bw,
    float* __restrict__ Cv, int K, int lda, int ldb, int ldc, int bm, int bn) {
  __shared__ u16 lA[128 * 32];
  __shared__ u16 lB[128 * 32];
  const int tid = threadIdx.x;
  const int w = tid >> 6, lane = tid & 63;
  const int wr = w >> 1, wc = w & 1;
  const int lr = lane & 15;
  const int lk = (lane >> 4) << 3;

  f32x4 acc[4][4] = {};

  const int c0 = tid, c1 = tid + 256;
  const size_t aoff0 = (size_t)(bm * 128 + (c0 >> 2)) * lda + ((c0 & 3) << 3);
  const size_t aoff1 = (size_t)(bm * 128 + (c1 >> 2)) * lda + ((c1 & 3) << 3);
  const size_t boff0 = (size_t)(bn * 128 + (c0 >> 2)) * ldb + ((c0 & 3) << 3);
  const size_t boff1 = (size_t)(bn * 128 + (c1 >> 2)) * ldb + ((c1 & 3) << 3);
  u16* lA0 = lA + c0 * 8; u16* lA1 = lA + c1 * 8;
  u16* lB0 = lB + c0 * 8; u16* lB1 = lB + c1 * 8;

  for (int k0 = 0; k0 < K; k0 += 32) {
    gload_lds16(A + aoff0 + k0, lA0);
    gload_lds16(A + aoff1 + k0, lA1);
    gload_lds16(Bw + boff0 + k0, lB0);
    gload_lds16(Bw + boff1 + k0, lB1);
    __syncthreads();
    bf16x8 aF[4], bF[4];
#pragma unroll
    for (int m = 0; m < 4; ++m)
      aF[m] = *reinterpret_cast<const bf16x8*>(&lA[(wr * 64 + m * 16 + lr) * 32 + lk]);
#pragma unroll
    for (int n = 0; n < 4; ++n)
      bF[n] = *reinterpret_cast<const bf16x8*>(&lB[(wc * 64 + n * 16 + lr) * 32 + lk]);
#pragma unroll
    for (int m = 0; m < 4; ++m)
#pragma unroll
      for (int n = 0; n < 4; ++n)
        acc[m][n] = __builtin_amdgcn_mfma_f32_16x16x32_bf16(aF[m], bF[n], acc[m][n], 0, 0, 0);
    __syncthreads();
  }

#pragma unroll
  for (int m = 0; m < 4; ++m) {
    const int row = bm * 128 + wr * 64 + m * 16 + ((lane >> 4) << 2);
#pragma unroll
    for (int n = 0; n < 4; ++n) {
      const int col = bn * 128 + wc * 64 + n * 16 + lr;
#pragma unroll
      for (int r = 0; r < 4; ++r)
        Cv[(size_t)(row + r) * ldc + col] = acc[m][n][r];
    }
  }
}

// ---- both weight GEMMs, split-K=2: z<2 -> Wqk slabs, z>=2 -> Wvo slabs ----
__global__ __launch_bounds__(256, 2)
void gemm_splitk_dual(const u16* __restrict__ wktb, const u16* __restrict__ wqtb,
                      const u16* __restrict__ wob, const u16* __restrict__ wvtb,
                      float* __restrict__ pk) {
  const int z = blockIdx.z;
  const u16 *A, *B;
  if (z < 2) { A = wktb + z * 512; B = wqtb + z * 512; }
  else       { A = wob + (z - 2) * 512; B = wvtb + (z - 2) * 512; }
  float* C = pk + (size_t)z * D_ * D_;
  gemm_core(A, B, C, 512, D_, D_, D_, blockIdx.x, blockIdx.y);
}

// ---------------- 128x128 bf16 NT GEMM (proven m97 structure; R6 baseline) ---
// C[i,j] = sum_k A[i,k]*Bw[j,k] (+bias[j]) (+bf16 xadd[i,j]); BK=32, 4 waves.
template<int OUT_BF16, int ADDX>
__global__ __launch_bounds__(256, 2)
void gemm_bt(const u16* __restrict__ A, const u16* __restrict__ Bw,
             const float* __restrict__ bias, const u16* __restrict__ xadd, int ldx,
             void* __restrict__ Cv, int K, int lda, int ldb, int ldc) {
  __shared__ u16 lA[128 * 32];
  __shared__ u16 lB[128 * 32];
  const int tid = threadIdx.x;
  const int bm = blockIdx.x, bn = blockIdx.y;
  const int w = tid >> 6, lane = tid & 63;
  const int wr = w >> 1, wc = w & 1;
  const int lr = lane & 15;
  const int lk = (lane >> 4) << 3;

  f32x4 acc[4][4] = {};

  const int c0 = tid, c1 = tid + 256;
  const size_t aoff0 = (size_t)(bm * 128 + (c0 >> 2)) * lda + ((c0 & 3) << 3);
  const size_t aoff1 = (size_t)(bm * 128 + (c1 >> 2)) * lda + ((c1 & 3) << 3);
  const size_t boff0 = (size_t)(bn * 128 + (c0 >> 2)) * ldb + ((c0 & 3) << 3);
  const size_t boff1 = (size_t)(bn * 128 + (c1 >> 2)) * ldb + ((c1 & 3) << 3);
  u16* lA0 = lA + c0 * 8; u16* lA1 = lA + c1 * 8;
  u16* lB0 = lB + c0 * 8; u16* lB1 = lB + c1 * 8;

  for (int k0 = 0; k0 < K; k0 += 32) {
    gload_lds16(A + aoff0 + k0, lA0);
    gload_lds16(A + aoff1 + k0, lA1);
    gload_lds16(Bw + boff0 + k0, lB0);
    gload_lds16(Bw + boff1 + k0, lB1);
    __syncthreads();
    bf16x8 aF[4], bF[4];
#pragma unroll
    for (int m = 0; m < 4; ++m)
      aF[m] = *reinterpret_cast<const bf16x8*>(&lA[(wr * 64 + m * 16 + lr) * 32 + lk]);
#pragma unroll
    for (int n = 0; n < 4; ++n)
      bF[n] = *reinterpret_cast<const bf16x8*>(&lB[(wc * 64 + n * 16 + lr) * 32 + lk]);
#pragma unroll
    for (int m = 0; m < 4; ++m)
#pragma unroll
      for (int n = 0; n < 4; ++n)
        acc[m][n] = __builtin_amdgcn_mfma_f32_16x16x32_bf16(aF[m], bF[n], acc[m][n], 0, 0, 0);
    __syncthreads();
  }

#pragma unroll
  for (int m = 0; m < 4; ++m) {
    const int row = bm * 128 + wr * 64 + m * 16 + ((lane >> 4) << 2);
#pragma unroll
    for (int n = 0; n < 4; ++n) {
      const int col = bn * 128 + wc * 64 + n * 16 + lr;
      const float bb = bias ? bias[col] : 0.f;
#pragma unroll
      for (int r = 0; r < 4; ++r) {
        float v = acc[m][n][r] + bb;
        if (ADDX) v += bf2f(xadd[(size_t)(row + r) * ldx + col]);
        if (OUT_BF16) ((u16*)Cv)[(size_t)(row + r) * ldc + col] = f2bf(v);
        else          ((float*)Cv)[(size_t)(row + r) * ldc + col] = v;
      }
    }
  }
}

// ---------------- attention over own-history slice (v5) ----------------------
__global__ __launch_bounds__(256, 2)
void attn_kernel(const u16* __restrict__ Q2, const float* __restrict__ hist,
                 const float* __restrict__ logb, u16* __restrict__ hw) {
  __shared__ u16 lh[H_ * D_];    // 64KB bf16 [h][d]
  __shared__ float sTab[4][H_];
  __shared__ float pTab[H_][4];
  const int t = blockIdx.x;
  const int tid = threadIdx.x;
  const int w = tid >> 6, lane = tid & 63;
  const float* hp = hist + (size_t)t * (H_ * D_);

  float s[32] = {};
#pragma unroll 2
  for (int c = 0; c < 4; ++c) {
    const int d0 = lane * 4 + 256 * c;
    float qf[4][4];
#pragma unroll
    for (int b = 0; b < 4; ++b) {
      ushort4 qv = *reinterpret_cast<const ushort4*>(Q2 + ((size_t)b * T_ + t) * 2048 + d0);
      qf[b][0] = bf2f(qv.x); qf[b][1] = bf2f(qv.y);
      qf[b][2] = bf2f(qv.z); qf[b][3] = bf2f(qv.w);
    }
#pragma unroll
    for (int i = 0; i < 8; ++i) {
      const int h = w * 8 + i;
      float4 hv = *reinterpret_cast<const float4*>(hp + h * D_ + d0);
      ushort4 hb;
      hb.x = f2bf(hv.x); hb.y = f2bf(hv.y); hb.z = f2bf(hv.z); hb.w = f2bf(hv.w);
      *reinterpret_cast<ushort4*>(&lh[h * D_ + d0]) = hb;
#pragma unroll
      for (int b = 0; b < 4; ++b)
        s[b * 8 + i] += qf[b][0] * hv.x + qf[b][1] * hv.y +
                        qf[b][2] * hv.z + qf[b][3] * hv.w;
    }
  }
#pragma unroll
  for (int m = 1; m < 64; m <<= 1)
#pragma unroll
    for (int j = 0; j < 32; ++j) s[j] += __shfl_xor(s[j], m);
  if (lane < 32)
    sTab[lane >> 3][w * 8 + (lane & 7)] = s[lane] * 0.03125f + logb[w * 8 + (lane & 7)];
  __syncthreads();

  if (tid < 128) {
    const int b = tid >> 5, h = tid & 31;
    float m0 = -1e30f;
#pragma unroll
    for (int j = 0; j < 32; ++j) m0 = fmaxf(m0, sTab[b][j]);
    float sm = 0.f;
#pragma unroll
    for (int j = 0; j < 32; ++j) sm += __expf(sTab[b][j] - m0);
    pTab[h][b] = __expf(sTab[b][h] - m0) / sm;
  }
  __syncthreads();

  float acc[4][4] = {};
#pragma unroll 8
  for (int h = 0; h < H_; ++h) {
    ushort4 hv = *reinterpret_cast<const ushort4*>(&lh[h * D_ + tid * 4]);
    const float h0 = bf2f(hv.x), h1 = bf2f(hv.y), h2 = bf2f(hv.z), h3 = bf2f(hv.w);
    f32x4 pv = *reinterpret_cast<const f32x4*>(&pTab[h][0]);
#pragma unroll
    for (int bb = 0; bb < 4; ++bb) {
      acc[bb][0] += pv[bb] * h0;
      acc[bb][1] += pv[bb] * h1;
      acc[bb][2] += pv[bb] * h2;
      acc[bb][3] += pv[bb] * h3;
    }
  }
#pragma unroll
  for (int bb = 0; bb < 4; ++bb) {
    ushort4 o;
    o.x = f2bf(acc[bb][0]); o.y = f2bf(acc[bb][1]);
    o.z = f2bf(acc[bb][2]); o.w = f2bf(acc[bb][3]);
    *reinterpret_cast<ushort4*>(hw + ((size_t)bb * T_ + t) * D_ + tid * 4) = o;
  }
}

extern "C" void kernel_launch(void* const* d_in, const int* in_sizes, int n_in,
                              void* d_out, int out_size, void* d_ws, size_t ws_size,
                              hipStream_t stream) {
  (void)in_sizes; (void)n_in; (void)out_size; (void)ws_size;
  const float* x     = (const float*)d_in[0];
  const float* hist  = (const float*)d_in[1];
  const float* Wq    = (const float*)d_in[2];
  const float* bq    = (const float*)d_in[3];
  const float* Wk    = (const float*)d_in[4];
  // d_in[5] = bk: exactly cancelled by softmax shift-invariance
  const float* Wv    = (const float*)d_in[6];
  const float* bv    = (const float*)d_in[7];
  const float* Wo    = (const float*)d_in[8];
  const float* bo    = (const float*)d_in[9];
  const float* decay = (const float*)d_in[10];

  char* p = (char*)d_ws;
  u16* wqtb = (u16*)p; p += (size_t)D_ * D_ * 2;      // Wq^T bf16
  u16* wktb = (u16*)p; p += (size_t)D_ * D_ * 2;      // Wk^T bf16
  u16* wvtb = (u16*)p; p += (size_t)D_ * D_ * 2;      // Wv^T bf16
  u16* wob  = (u16*)p; p += (size_t)D_ * D_ * 2;      // Wo bf16
  u16* wvo  = (u16*)p; p += (size_t)D_ * D_ * 2;      // Wo@Wv bf16
  u16* b2w  = (u16*)p; p += (size_t)2 * D_ * D_ * 2;  // [Wqk ; Wo] rows, ldb=1024
  float* bias2  = (float*)p; p += 2 * D_ * 4;         // [bq@Wk | zeros]
  float* logb   = (float*)p; p += 4096;
  float* bvo    = (float*)p; p += 4096;               // bv@Wo^T + bo
  float* b2part = (float*)p; p += 16 * D_ * 4;
  float* pk     = (float*)p; p += (size_t)4 * D_ * D_ * 4;  // split-K=2 partials (16MB)
  u16* xb   = (u16*)p; p += (size_t)B_ * T_ * D_ * 2;       // x bf16
  u16* Q2b  = (u16*)p; p += (size_t)B_ * T_ * 2048 * 2;     // [Q2 | xo] bf16, ldc=2048
  u16* hwb  = (u16*)p; p += (size_t)B_ * T_ * D_ * 2;       // attn output bf16

  const int M = B_ * T_;  // 8192

  megaprep<<<6464, 256, 0, stream>>>(x, Wq, Wk, Wv, Wo, bq, bv, bo,
                                     xb, wqtb, wktb, wvtb, wob, b2w, b2part, bvo);
  gemm_splitk_dual<<<dim3(8, 8, 4), 256, 0, stream>>>(wktb, wqtb, wob, wvtb, pk);
  finish_kernel<<<2052, 256, 0, stream>>>(pk, b2part, decay, b2w, wvo, bias2, logb);

  // GEMM1: [Q2 | xo] = xb @ b2w^T + [bias2 | 0]  (M=8192,N=2048,K=1024; 1024 blocks)
  gemm_bt<1, 0><<<dim3(M / 128, 2048 / 128), 256, 0, stream>>>(
      xb, b2w, bias2, nullptr, 0, Q2b, D_, D_, D_, 2048);
  // attention -> hw
  attn_kernel<<<T_, 256, 0, stream>>>(Q2b, hist, logb, hwb);
  // out = hw @ wvo^T + xo + bvo  (M=8192,N=1024,K=1024; 512 blocks, f32 out)
  gemm_bt<0, 1><<<dim3(M / 128, D_ / 128), 256, 0, stream>>>(
      hwb, wvo, bvo, Q2b + 1024, 2048, (float*)d_out, D_, D_, D_, D_);
}